// Round 1
// baseline (53217.230 us; speedup 1.0000x reference)
//
#include <hip/hip_runtime.h>
#include <math.h>

#define D 512
#define THRESH 0.5f
#define NMAX 8192
#define BM 64
#define BN 64
#define BK 16

__global__ void k_init(int* dn, int n) { *dn = n; }

// one block (128 threads) per row: norm = max(||row||, 1e-8)
__global__ void k_norms(const float* __restrict__ embs, float* __restrict__ norms,
                        const int* __restrict__ dn) {
    int n = *dn;
    int row = blockIdx.x;
    if (row >= n) return;
    int t = threadIdx.x; // 0..127
    float4 v = ((const float4*)(embs + (size_t)row * D))[t];
    float s = v.x * v.x + v.y * v.y + v.z * v.z + v.w * v.w;
    #pragma unroll
    for (int o = 32; o > 0; o >>= 1) s += __shfl_down(s, o, 64);
    __shared__ float ls[2];
    if ((t & 63) == 0) ls[t >> 6] = s;
    __syncthreads();
    if (t == 0) norms[row] = fmaxf(sqrtf(ls[0] + ls[1]), 1e-8f);
}

// sim tile: sim[r][j] = dot(E[tile_start+r], E[j]) / (norms[i]*norms[j])
// block computes 64x64, 16x16 threads, 4x4 per thread, fp32
__global__ void k_simtile(const float* __restrict__ E, const float* __restrict__ norms,
                          float* __restrict__ sim, int tile_start, int TR, int simStride,
                          const int* __restrict__ dn) {
    int n = *dn;
    if (tile_start >= n) return;
    int bm = blockIdx.y * BM;       // row offset within tile
    int bn = blockIdx.x * BN;       // global col
    int row0 = tile_start + bm;
    if (row0 >= n || bn >= n) return;

    __shared__ float As[BK][BM + 1];
    __shared__ float Bs[BK][BN + 1];
    int tx = threadIdx.x, ty = threadIdx.y;
    int tid = ty * 16 + tx;
    float acc[4][4] = {};

    for (int k0 = 0; k0 < D; k0 += BK) {
        int m  = tid >> 2;            // 0..63
        int kk = (tid & 3) * 4;       // 0,4,8,12
        int gr = row0 + m;
        float4 va = make_float4(0.f, 0.f, 0.f, 0.f);
        if (gr < n) va = *(const float4*)(E + (size_t)gr * D + k0 + kk);
        As[kk + 0][m] = va.x; As[kk + 1][m] = va.y; As[kk + 2][m] = va.z; As[kk + 3][m] = va.w;
        int gc = bn + m;
        float4 vb = make_float4(0.f, 0.f, 0.f, 0.f);
        if (gc < n) vb = *(const float4*)(E + (size_t)gc * D + k0 + kk);
        Bs[kk + 0][m] = vb.x; Bs[kk + 1][m] = vb.y; Bs[kk + 2][m] = vb.z; Bs[kk + 3][m] = vb.w;
        __syncthreads();
        #pragma unroll
        for (int k = 0; k < BK; ++k) {
            float a[4], b[4];
            #pragma unroll
            for (int u = 0; u < 4; ++u) { a[u] = As[k][ty * 4 + u]; b[u] = Bs[k][tx * 4 + u]; }
            #pragma unroll
            for (int u = 0; u < 4; ++u)
                #pragma unroll
                for (int w = 0; w < 4; ++w)
                    acc[u][w] = fmaf(a[u], b[w], acc[u][w]);
        }
        __syncthreads();
    }

    #pragma unroll
    for (int u = 0; u < 4; ++u) {
        int r = bm + ty * 4 + u;           // row within tile
        int gi = tile_start + r;
        if (gi >= n || r >= TR) continue;
        float ni = norms[gi];
        #pragma unroll
        for (int w = 0; w < 4; ++w) {
            int j = bn + tx * 4 + w;
            if (j >= n) continue;
            sim[(size_t)r * simStride + j] = acc[u][w] / (ni * norms[j]);
        }
    }
}

// sequential greedy scan over rows of this tile. Single block, 1024 threads.
// merged flags kept as bitmask in LDS, persisted to gmask across tiles.
__global__ void __launch_bounds__(1024)
k_scan(const float* __restrict__ sim, int tile_start, int TR, int simStride,
       unsigned int* __restrict__ gmask, int* __restrict__ partner,
       int* __restrict__ consumed, const int* __restrict__ dn) {
    int n = *dn;
    if (tile_start >= n) return;
    int t = threadIdx.x;
    __shared__ unsigned int mask[NMAX / 32];
    __shared__ float wval[16];
    __shared__ int   widx[16];
    if (t < NMAX / 32) mask[t] = (tile_start == 0) ? 0u : gmask[t];
    __syncthreads();

    int rows = min(TR, n - tile_start);
    for (int r = 0; r < rows; ++r) {
        int i = tile_start + r;
        const float* srow = sim + (size_t)r * simStride;
        float bv = -INFINITY;
        int   bi = 0x7fffffff;
        for (int j = i + 1 + t; j < n; j += 1024) {
            if (!((mask[j >> 5] >> (j & 31)) & 1u)) {
                float v = srow[j];
                if (v > bv) { bv = v; bi = j; }   // ascending j: strict > keeps first max
            }
        }
        // wave reduce (max, tie -> smaller index)
        #pragma unroll
        for (int o = 32; o > 0; o >>= 1) {
            float ov = __shfl_down(bv, o, 64);
            int   oi = __shfl_down(bi, o, 64);
            if (ov > bv || (ov == bv && oi < bi)) { bv = ov; bi = oi; }
        }
        if ((t & 63) == 0) { wval[t >> 6] = bv; widx[t >> 6] = bi; }
        __syncthreads();
        if (t == 0) {
            float fv = wval[0]; int fi = widx[0];
            for (int w = 1; w < 16; ++w)
                if (wval[w] > fv || (wval[w] == fv && widx[w] < fi)) { fv = wval[w]; fi = widx[w]; }
            unsigned int was = (mask[i >> 5] >> (i & 31)) & 1u;
            consumed[i] = (int)was;
            int ok = (!was) && (fv >= THRESH);
            partner[i] = ok ? fi : -1;
            if (ok) {
                mask[i >> 5]  |= 1u << (i & 31);
                mask[fi >> 5] |= 1u << (fi & 31);
            }
        }
        __syncthreads();
    }
    if (t < NMAX / 32) gmask[t] = mask[t];
}

// survivor compaction plan: srcIdx[k] = i for each surviving row, dn <- newN
__global__ void __launch_bounds__(1024)
k_compact_plan(const int* __restrict__ consumed, int* __restrict__ srcIdx,
               int* __restrict__ dn) {
    int n = *dn;
    int t = threadIdx.x;
    __shared__ int lds[1024];
    __shared__ int base;
    if (t == 0) base = 0;
    __syncthreads();
    for (int c0 = 0; c0 < n; c0 += 1024) {
        int i = c0 + t;
        int f = (i < n) ? (consumed[i] ? 0 : 1) : 0;
        lds[t] = f;
        __syncthreads();
        for (int o = 1; o < 1024; o <<= 1) {
            int v = (t >= o) ? lds[t - o] : 0;
            __syncthreads();
            lds[t] += v;
            __syncthreads();
        }
        if (f) srcIdx[base + lds[t] - 1] = i;
        __syncthreads();
        if (t == 0) base += lds[1023];
        __syncthreads();
    }
    if (t == 0) *dn = base;
}

// fused[i] = partner>=0 ? min(e_i + e_p, 1) : e_i ; compact into nxt
__global__ void k_fuse(const float* __restrict__ cur, float* __restrict__ nxt,
                       const int* __restrict__ srcIdx, const int* __restrict__ partner,
                       const int* __restrict__ dn) {
    int nn = *dn;            // new count (already updated)
    int k = blockIdx.x;
    if (k >= nn) return;
    int t = threadIdx.x;     // 0..127
    int i = srcIdx[k];
    int p = partner[i];
    float4 v = ((const float4*)(cur + (size_t)i * D))[t];
    if (p >= 0) {
        float4 w = ((const float4*)(cur + (size_t)p * D))[t];
        v.x = fminf(v.x + w.x, 1.0f);
        v.y = fminf(v.y + w.y, 1.0f);
        v.z = fminf(v.z + w.z, 1.0f);
        v.w = fminf(v.w + w.w, 1.0f);
    }
    ((float4*)(nxt + (size_t)k * D))[t] = v;
}

__global__ void k_copyout(const float* __restrict__ src, float* __restrict__ dst, int nelem) {
    int i = blockIdx.x * 256 + threadIdx.x;
    if (i < nelem) dst[i] = src[i];
}

extern "C" void kernel_launch(void* const* d_in, const int* in_sizes, int n_in,
                              void* d_out, int out_size, void* d_ws, size_t ws_size,
                              hipStream_t stream) {
    const float* input = (const float*)d_in[0];
    const int N0 = in_sizes[0] / D;   // 8192
    char* ws = (char*)d_ws;

    const size_t embBytes = (size_t)N0 * D * sizeof(float);   // 16 MB
    float* bufA = (float*)ws;
    float* bufB = (float*)(ws + embBytes);
    char*  aux  = ws + 2 * embBytes;
    float* norms          = (float*)(aux);
    int*   partner        = (int*)(aux + 32 * 1024);
    int*   consumed       = (int*)(aux + 64 * 1024);
    int*   srcIdx         = (int*)(aux + 96 * 1024);
    unsigned int* gmask   = (unsigned int*)(aux + 128 * 1024);
    int*   dn             = (int*)(aux + 130 * 1024);
    float* simTile        = (float*)(aux + 192 * 1024);
    const size_t fixedBytes = 2 * embBytes + 192 * 1024;

    // pick largest tile height that fits the workspace
    int TR = NMAX;
    while (TR > 64 && fixedBytes + (size_t)TR * N0 * sizeof(float) > ws_size) TR >>= 1;

    const int ROUNDS = 16;
    k_init<<<1, 1, 0, stream>>>(dn, N0);
    for (int r = 0; r < ROUNDS; ++r) {
        const float* cur = (r == 0) ? input : ((r & 1) ? bufA : bufB);
        float* nxt = (r & 1) ? bufB : bufA;
        k_norms<<<N0, 128, 0, stream>>>(cur, norms, dn);
        int NT = N0 / TR;
        for (int t = 0; t < NT; ++t) {
            dim3 g(N0 / BN, (TR + BM - 1) / BM);
            k_simtile<<<g, dim3(16, 16), 0, stream>>>(cur, norms, simTile, t * TR, TR, N0, dn);
            k_scan<<<1, 1024, 0, stream>>>(simTile, t * TR, TR, N0, gmask, partner, consumed, dn);
        }
        k_compact_plan<<<1, 1024, 0, stream>>>(consumed, srcIdx, dn);
        k_fuse<<<N0, 128, 0, stream>>>(cur, nxt, srcIdx, partner, dn);
    }
    float* fin = ((ROUNDS - 1) & 1) ? bufB : bufA;
    k_copyout<<<(out_size + 255) / 256, 256, 0, stream>>>(fin, (float*)d_out, out_size);
}

// Round 2
// 23568.365 us; speedup vs baseline: 2.2580x; 2.2580x over previous
//
#include <hip/hip_runtime.h>
#include <math.h>

#define D 512
#define THRESH 0.5f
#define NMAX 8192
#define BM 64
#define BN 64
#define BK 16
#define TOPK 64

__global__ void k_init(int* dn, int n) { *dn = n; }

// one block (128 threads) per row: norm = max(||row||, 1e-8)
__global__ void k_norms(const float* __restrict__ embs, float* __restrict__ norms,
                        const int* __restrict__ dn) {
    int n = *dn;
    int row = blockIdx.x;
    if (row >= n) return;
    int t = threadIdx.x; // 0..127
    float4 v = ((const float4*)(embs + (size_t)row * D))[t];
    float s = v.x * v.x + v.y * v.y + v.z * v.z + v.w * v.w;
    #pragma unroll
    for (int o = 32; o > 0; o >>= 1) s += __shfl_down(s, o, 64);
    __shared__ float ls[2];
    if ((t & 63) == 0) ls[t >> 6] = s;
    __syncthreads();
    if (t == 0) norms[row] = fmaxf(sqrtf(ls[0] + ls[1]), 1e-8f);
}

// sim tile: sim[r][j] = dot(E[tile_start+r], E[j]) / (norms[i]*norms[j])
__global__ void k_simtile(const float* __restrict__ E, const float* __restrict__ norms,
                          float* __restrict__ sim, int tile_start, int TR, int simStride,
                          const int* __restrict__ dn) {
    int n = *dn;
    if (tile_start >= n) return;
    int bm = blockIdx.y * BM;       // row offset within tile
    int bn = blockIdx.x * BN;       // global col
    int row0 = tile_start + bm;
    if (row0 >= n || bn >= n) return;
    // triangle skip: only j > i is ever read downstream; max j in block = bn+BN-1,
    // min i in block = row0 -> skip when bn+BN-1 <= row0
    if (bn + BN <= row0 + 1) return;

    __shared__ float As[BK][BM + 1];
    __shared__ float Bs[BK][BN + 1];
    int tx = threadIdx.x, ty = threadIdx.y;
    int tid = ty * 16 + tx;
    float acc[4][4] = {};

    for (int k0 = 0; k0 < D; k0 += BK) {
        int m  = tid >> 2;            // 0..63
        int kk = (tid & 3) * 4;       // 0,4,8,12
        int gr = row0 + m;
        float4 va = make_float4(0.f, 0.f, 0.f, 0.f);
        if (gr < n) va = *(const float4*)(E + (size_t)gr * D + k0 + kk);
        As[kk + 0][m] = va.x; As[kk + 1][m] = va.y; As[kk + 2][m] = va.z; As[kk + 3][m] = va.w;
        int gc = bn + m;
        float4 vb = make_float4(0.f, 0.f, 0.f, 0.f);
        if (gc < n) vb = *(const float4*)(E + (size_t)gc * D + k0 + kk);
        Bs[kk + 0][m] = vb.x; Bs[kk + 1][m] = vb.y; Bs[kk + 2][m] = vb.z; Bs[kk + 3][m] = vb.w;
        __syncthreads();
        #pragma unroll
        for (int k = 0; k < BK; ++k) {
            float a[4], b[4];
            #pragma unroll
            for (int u = 0; u < 4; ++u) { a[u] = As[k][ty * 4 + u]; b[u] = Bs[k][tx * 4 + u]; }
            #pragma unroll
            for (int u = 0; u < 4; ++u)
                #pragma unroll
                for (int w = 0; w < 4; ++w)
                    acc[u][w] = fmaf(a[u], b[w], acc[u][w]);
        }
        __syncthreads();
    }

    #pragma unroll
    for (int u = 0; u < 4; ++u) {
        int r = bm + ty * 4 + u;
        int gi = tile_start + r;
        if (gi >= n || r >= TR) continue;
        float ni = norms[gi];
        #pragma unroll
        for (int w = 0; w < 4; ++w) {
            int j = bn + tx * 4 + w;
            if (j >= n) continue;
            sim[(size_t)r * simStride + j] = acc[u][w] / (ni * norms[j]);
        }
    }
}

// per-row exact top-64 (val desc, idx asc) among j>i. One wave per row.
// Per-lane top-8 + overflow watermark; rows where watermark could intrude
// into the global top-64 get flagged for the exact fix kernel.
__global__ void __launch_bounds__(64) k_topk(
    const float* __restrict__ sim, int tile_start, int TR, int simStride,
    float* __restrict__ tkV, int* __restrict__ tkI, int* __restrict__ needFix,
    const int* __restrict__ dn)
{
    int n = *dn;
    int r = blockIdx.x;
    int i = tile_start + r;
    if (r >= TR || i >= n) return;
    int lane = threadIdx.x;
    const float* srow = sim + (size_t)r * simStride;

    float v[8]; int id[8];
    #pragma unroll
    for (int u = 0; u < 8; ++u) { v[u] = -INFINITY; id[u] = 0x7fffffff; }
    float ovV = -INFINITY; int ovI = 0x7fffffff;

    for (int j = i + 1 + lane; j < n; j += 64) {
        float x = srow[j];
        if (x > v[7] || (x == v[7] && j < id[7])) {
            // displaced element joins overflow watermark
            if (v[7] > ovV || (v[7] == ovV && id[7] < ovI)) { ovV = v[7]; ovI = id[7]; }
            int p = 7;
            #pragma unroll
            for (int u = 6; u >= 0; --u) {
                bool mv = (x > v[u]) || (x == v[u] && j < id[u]);   // monotone in u
                if (mv) { v[u + 1] = v[u]; id[u + 1] = id[u]; p = u; }
            }
            v[p] = x; id[p] = j;
        } else {
            if (x > ovV || (x == ovV && j < ovI)) { ovV = x; ovI = j; }
        }
    }

    // merge: 64 rounds of lexicographic wave-max over per-lane sorted heads
    int pos = 0;
    float myV = -INFINITY; int myI = 0x7fffffff;
    for (int k = 0; k < TOPK; ++k) {
        float hv = (pos < 8) ? v[pos] : -INFINITY;
        int   hi = (pos < 8) ? id[pos] : 0x7fffffff;
        float bv = hv; int bi = hi;
        #pragma unroll
        for (int o = 1; o < 64; o <<= 1) {
            float xv = __shfl_xor(bv, o, 64);
            int   xi = __shfl_xor(bi, o, 64);
            if (xv > bv || (xv == bv && xi < bi)) { bv = xv; bi = xi; }
        }
        if (pos < 8 && hv == bv && hi == bi) pos++;
        if (k == lane) { myV = bv; myI = bi; }
    }
    tkV[(size_t)i * TOPK + lane] = myV;
    tkI[(size_t)i * TOPK + lane] = myI;

    // exactness check: v64 vs max overflow
    float v64 = __shfl(myV, 63, 64);
    int   i64 = __shfl(myI, 63, 64);
    float oV = ovV; int oI = ovI;
    #pragma unroll
    for (int o = 1; o < 64; o <<= 1) {
        float xv = __shfl_xor(oV, o, 64);
        int   xi = __shfl_xor(oI, o, 64);
        if (xv > oV || (xv == oV && xi < oI)) { oV = xv; oI = xi; }
    }
    int bad = (oV > v64) || (oV == v64 && oI < i64);
    if (lane == 0) needFix[i] = bad;
}

// rare exact redo: per-lane top-64 lists in LDS (unconditionally exact)
__global__ void __launch_bounds__(64) k_topkfix(
    const float* __restrict__ sim, int tile_start, int TR, int simStride,
    float* __restrict__ tkV, int* __restrict__ tkI, const int* __restrict__ needFix,
    const int* __restrict__ dn)
{
    int n = *dn;
    int r = blockIdx.x;
    int i = tile_start + r;
    if (r >= TR || i >= n) return;
    if (!needFix[i]) return;
    int lane = threadIdx.x;
    __shared__ float lv[64][TOPK];
    __shared__ int   li[64][TOPK];
    for (int u = 0; u < TOPK; ++u) { lv[lane][u] = -INFINITY; li[lane][u] = 0x7fffffff; }
    const float* srow = sim + (size_t)r * simStride;
    for (int j = i + 1 + lane; j < n; j += 64) {
        float x = srow[j];
        float wv = lv[lane][TOPK - 1]; int wi = li[lane][TOPK - 1];
        if (x > wv || (x == wv && j < wi)) {
            int p = TOPK - 1;
            for (int u = TOPK - 2; u >= 0; --u) {
                float uv = lv[lane][u]; int ui = li[lane][u];
                if (x > uv || (x == uv && j < ui)) { lv[lane][u + 1] = uv; li[lane][u + 1] = ui; p = u; }
                else break;
            }
            lv[lane][p] = x; li[lane][p] = j;
        }
    }
    int pos = 0;
    float myV = -INFINITY; int myI = 0x7fffffff;
    for (int k = 0; k < TOPK; ++k) {
        float hv = (pos < TOPK) ? lv[lane][pos] : -INFINITY;
        int   hi = (pos < TOPK) ? li[lane][pos] : 0x7fffffff;
        float bv = hv; int bi = hi;
        #pragma unroll
        for (int o = 1; o < 64; o <<= 1) {
            float xv = __shfl_xor(bv, o, 64);
            int   xi = __shfl_xor(bi, o, 64);
            if (xv > bv || (xv == bv && xi < bi)) { bv = xv; bi = xi; }
        }
        if (pos < TOPK && hv == bv && hi == bi) pos++;
        if (k == lane) { myV = bv; myI = bi; }
    }
    tkV[(size_t)i * TOPK + lane] = myV;
    tkI[(size_t)i * TOPK + lane] = myI;
}

// serial greedy scan over ALL rows, one wave. Per row: load 64 candidates,
// ballot first unmerged. Fallback (all-64-consumed && U>0): recompute sims
// against enumerated unmerged suffix.
__global__ void __launch_bounds__(64) k_scan2(
    const float* __restrict__ tkV, const int* __restrict__ tkI,
    const float* __restrict__ E, const float* __restrict__ norms,
    int* __restrict__ partner, int* __restrict__ consumed,
    const int* __restrict__ dn)
{
    int n = *dn;
    int lane = threadIdx.x;
    __shared__ unsigned int mask[NMAX / 32];
    __shared__ int lsCnt;
    __shared__ int lsIdx[2048];
    for (int w = lane; w < NMAX / 32; w += 64) mask[w] = 0u;
    __syncthreads();

    int U = n - 1;   // unmerged count in suffix {j > i}, uniform across lanes
    float cV = (n > 0) ? tkV[lane] : -INFINITY;
    int   cI = (n > 0) ? tkI[lane] : 0x7fffffff;

    for (int i = 0; i < n; ++i) {
        float nV = -INFINITY; int nI = 0x7fffffff;
        if (i + 1 < n) {   // prefetch next row's candidate list
            nV = tkV[(size_t)(i + 1) * TOPK + lane];
            nI = tkI[(size_t)(i + 1) * TOPK + lane];
        }
        unsigned int was = (mask[i >> 5] >> (i & 31)) & 1u;
        if (!was) {
            float bv = -INFINITY; int j = -1;
            bool unm = (cI < n) && !((mask[cI >> 5] >> (cI & 31)) & 1u);
            unsigned long long bal = __ballot(unm);
            if (bal) {
                int l = __builtin_ctzll(bal);   // list sorted: lowest lane = lex-max
                bv = __shfl(cV, l, 64);
                j  = __shfl(cI, l, 64);
            } else if (U > 0) {
                // fallback: exact argmax over unmerged suffix via recomputed dots
                float ni = norms[i];
                float4 ei0 = *(const float4*)(E + (size_t)i * D + lane * 8);
                float4 ei1 = *(const float4*)(E + (size_t)i * D + lane * 8 + 4);
                float bbv = -INFINITY; int bbj = 0x7fffffff;
                int w0 = (i + 1) >> 5;
                int wN = (n + 31) >> 5;
                for (int wb = w0; wb < wN; wb += 64) {
                    if (lane == 0) lsCnt = 0;
                    int w = wb + lane;
                    unsigned int um = 0u;
                    if (w < wN) {
                        um = ~mask[w];
                        int jbase = w << 5;
                        if (jbase <= i) {
                            int k = i - jbase + 1;
                            um &= (k >= 32) ? 0u : (0xffffffffu << k);
                        }
                        int over = jbase + 32 - n;
                        if (over > 0) um &= (over >= 32) ? 0u : (0xffffffffu >> over);
                    }
                    while (um) {
                        int b = __builtin_ctz(um);
                        um &= um - 1;
                        int slot = atomicAdd(&lsCnt, 1);
                        lsIdx[slot] = (w << 5) + b;
                    }
                    int cnt = lsCnt;
                    for (int c = 0; c < cnt; ++c) {
                        int jj = lsIdx[c];
                        float4 a0 = *(const float4*)(E + (size_t)jj * D + lane * 8);
                        float4 a1 = *(const float4*)(E + (size_t)jj * D + lane * 8 + 4);
                        float s = ei0.x * a0.x + ei0.y * a0.y + ei0.z * a0.z + ei0.w * a0.w
                                + ei1.x * a1.x + ei1.y * a1.y + ei1.z * a1.z + ei1.w * a1.w;
                        #pragma unroll
                        for (int o = 1; o < 64; o <<= 1) s += __shfl_xor(s, o, 64);
                        float sv = s / (ni * norms[jj]);
                        if (sv > bbv || (sv == bbv && jj < bbj)) { bbv = sv; bbj = jj; }
                    }
                }
                if (bbj < n) { bv = bbv; j = bbj; }
            }
            int ok = (j >= 0) && (bv >= THRESH);
            if (ok) {
                mask[i >> 5] |= 1u << (i & 31);     // uniform value, all lanes
                mask[j >> 5] |= 1u << (j & 31);
                U -= 1;
                if (lane == 0) { partner[i] = j; consumed[i] = 0; }
            } else {
                if (lane == 0) { partner[i] = -1; consumed[i] = 0; }
            }
        } else {
            if (lane == 0) { partner[i] = -1; consumed[i] = 1; }
        }
        if (i + 1 < n) {
            unsigned int b = (mask[(i + 1) >> 5] >> ((i + 1) & 31)) & 1u;
            U -= (b ? 0 : 1);
        }
        cV = nV; cI = nI;
    }
}

// survivor compaction plan: srcIdx[k] = i for each surviving row, dn <- newN
__global__ void __launch_bounds__(1024)
k_compact_plan(const int* __restrict__ consumed, int* __restrict__ srcIdx,
               int* __restrict__ dn) {
    int n = *dn;
    int t = threadIdx.x;
    __shared__ int lds[1024];
    __shared__ int base;
    if (t == 0) base = 0;
    __syncthreads();
    for (int c0 = 0; c0 < n; c0 += 1024) {
        int i = c0 + t;
        int f = (i < n) ? (consumed[i] ? 0 : 1) : 0;
        lds[t] = f;
        __syncthreads();
        for (int o = 1; o < 1024; o <<= 1) {
            int v = (t >= o) ? lds[t - o] : 0;
            __syncthreads();
            lds[t] += v;
            __syncthreads();
        }
        if (f) srcIdx[base + lds[t] - 1] = i;
        __syncthreads();
        if (t == 0) base += lds[1023];
        __syncthreads();
    }
    if (t == 0) *dn = base;
}

// fused[i] = partner>=0 ? min(e_i + e_p, 1) : e_i ; compact into nxt
__global__ void k_fuse(const float* __restrict__ cur, float* __restrict__ nxt,
                       const int* __restrict__ srcIdx, const int* __restrict__ partner,
                       const int* __restrict__ dn) {
    int nn = *dn;            // new count (already updated)
    int k = blockIdx.x;
    if (k >= nn) return;
    int t = threadIdx.x;     // 0..127
    int i = srcIdx[k];
    int p = partner[i];
    float4 v = ((const float4*)(cur + (size_t)i * D))[t];
    if (p >= 0) {
        float4 w = ((const float4*)(cur + (size_t)p * D))[t];
        v.x = fminf(v.x + w.x, 1.0f);
        v.y = fminf(v.y + w.y, 1.0f);
        v.z = fminf(v.z + w.z, 1.0f);
        v.w = fminf(v.w + w.w, 1.0f);
    }
    ((float4*)(nxt + (size_t)k * D))[t] = v;
}

__global__ void k_copyout(const float* __restrict__ src, float* __restrict__ dst, int nelem) {
    int i = blockIdx.x * 256 + threadIdx.x;
    if (i < nelem) dst[i] = src[i];
}

extern "C" void kernel_launch(void* const* d_in, const int* in_sizes, int n_in,
                              void* d_out, int out_size, void* d_ws, size_t ws_size,
                              hipStream_t stream) {
    const float* input = (const float*)d_in[0];
    const int N0 = in_sizes[0] / D;   // 8192
    char* ws = (char*)d_ws;

    // round 0 reads d_in directly; bufA holds <=N0/2 rows, bufB <=N0/4 rows
    const size_t embA = (size_t)(N0 / 2) * D * sizeof(float);   // 8 MB
    const size_t embB = (size_t)(N0 / 4) * D * sizeof(float);   // 4 MB
    float* bufA = (float*)ws;
    float* bufB = (float*)(ws + embA);
    char*  aux  = ws + embA + embB;
    float* norms        = (float*)(aux);
    int*   partner      = (int*)(aux + 32 * 1024);
    int*   consumed     = (int*)(aux + 64 * 1024);
    int*   srcIdx       = (int*)(aux + 96 * 1024);
    int*   dn           = (int*)(aux + 128 * 1024);
    int*   needFix      = (int*)(aux + 160 * 1024);
    float* tkV          = (float*)(aux + 256 * 1024);
    int*   tkI          = (int*)(aux + 256 * 1024 + (size_t)NMAX * TOPK * 4);
    float* simTile      = (float*)(aux + 256 * 1024 + 2 * (size_t)NMAX * TOPK * 4);
    const size_t fixedBytes = embA + embB + 256 * 1024 + 2 * (size_t)NMAX * TOPK * 4;

    int TR = NMAX;
    while (TR > 64 && fixedBytes + (size_t)TR * N0 * sizeof(float) > ws_size) TR >>= 1;

    const int ROUNDS = 16;
    k_init<<<1, 1, 0, stream>>>(dn, N0);
    for (int r = 0; r < ROUNDS; ++r) {
        const float* cur = (r == 0) ? input : ((r & 1) ? bufA : bufB);
        float* nxt = (r & 1) ? bufB : bufA;
        k_norms<<<N0, 128, 0, stream>>>(cur, norms, dn);
        int NT = N0 / TR;
        for (int t = 0; t < NT; ++t) {
            dim3 g(N0 / BN, TR / BM);
            k_simtile<<<g, dim3(16, 16), 0, stream>>>(cur, norms, simTile, t * TR, TR, N0, dn);
            k_topk<<<TR, 64, 0, stream>>>(simTile, t * TR, TR, N0, tkV, tkI, needFix, dn);
            k_topkfix<<<TR, 64, 0, stream>>>(simTile, t * TR, TR, N0, tkV, tkI, needFix, dn);
        }
        k_scan2<<<1, 64, 0, stream>>>(tkV, tkI, cur, norms, partner, consumed, dn);
        k_compact_plan<<<1, 1024, 0, stream>>>(consumed, srcIdx, dn);
        k_fuse<<<N0, 128, 0, stream>>>(cur, nxt, srcIdx, partner, dn);
    }
    float* fin = bufB;   // ROUNDS-1 = 15 is odd -> last write went to bufB
    k_copyout<<<(out_size + 255) / 256, 256, 0, stream>>>(fin, (float*)d_out, out_size);
}

// Round 4
// 22429.309 us; speedup vs baseline: 2.3727x; 1.0508x over previous
//
#include <hip/hip_runtime.h>
#include <math.h>

#define D 512
#define THRESH 0.5f
#define NMAX 8192
#define BM 64
#define BN 64
#define BK 16
#define TOPK 64

__global__ void k_init(int* dn, int n) { *dn = n; }

// one block (128 threads) per row: norm = max(||row||, 1e-8)
__global__ void k_norms(const float* __restrict__ embs, float* __restrict__ norms,
                        const int* __restrict__ dn) {
    int n = *dn;
    int row = blockIdx.x;
    if (row >= n) return;
    int t = threadIdx.x; // 0..127
    float4 v = ((const float4*)(embs + (size_t)row * D))[t];
    float s = v.x * v.x + v.y * v.y + v.z * v.z + v.w * v.w;
    #pragma unroll
    for (int o = 32; o > 0; o >>= 1) s += __shfl_down(s, o, 64);
    __shared__ float ls[2];
    if ((t & 63) == 0) ls[t >> 6] = s;
    __syncthreads();
    if (t == 0) norms[row] = fmaxf(sqrtf(ls[0] + ls[1]), 1e-8f);
}

// sim tile: sim[r][j] = dot(E[tile_start+r], E[j]) / (norms[i]*norms[j])
__global__ void k_simtile(const float* __restrict__ E, const float* __restrict__ norms,
                          float* __restrict__ sim, int tile_start, int TR, int simStride,
                          const int* __restrict__ dn) {
    int n = *dn;
    if (tile_start >= n) return;
    int bm = blockIdx.y * BM;       // row offset within tile
    int bn = blockIdx.x * BN;       // global col
    int row0 = tile_start + bm;
    if (row0 >= n || bn >= n) return;
    // triangle skip: only j > i is ever read downstream
    if (bn + BN <= row0 + 1) return;

    __shared__ float As[BK][BM + 1];
    __shared__ float Bs[BK][BN + 1];
    int tx = threadIdx.x, ty = threadIdx.y;
    int tid = ty * 16 + tx;
    float acc[4][4] = {};

    for (int k0 = 0; k0 < D; k0 += BK) {
        int m  = tid >> 2;            // 0..63
        int kk = (tid & 3) * 4;       // 0,4,8,12
        int gr = row0 + m;
        float4 va = make_float4(0.f, 0.f, 0.f, 0.f);
        if (gr < n) va = *(const float4*)(E + (size_t)gr * D + k0 + kk);
        As[kk + 0][m] = va.x; As[kk + 1][m] = va.y; As[kk + 2][m] = va.z; As[kk + 3][m] = va.w;
        int gc = bn + m;
        float4 vb = make_float4(0.f, 0.f, 0.f, 0.f);
        if (gc < n) vb = *(const float4*)(E + (size_t)gc * D + k0 + kk);
        Bs[kk + 0][m] = vb.x; Bs[kk + 1][m] = vb.y; Bs[kk + 2][m] = vb.z; Bs[kk + 3][m] = vb.w;
        __syncthreads();
        #pragma unroll
        for (int k = 0; k < BK; ++k) {
            float a[4], b[4];
            #pragma unroll
            for (int u = 0; u < 4; ++u) { a[u] = As[k][ty * 4 + u]; b[u] = Bs[k][tx * 4 + u]; }
            #pragma unroll
            for (int u = 0; u < 4; ++u)
                #pragma unroll
                for (int w = 0; w < 4; ++w)
                    acc[u][w] = fmaf(a[u], b[w], acc[u][w]);
        }
        __syncthreads();
    }

    #pragma unroll
    for (int u = 0; u < 4; ++u) {
        int r = bm + ty * 4 + u;
        int gi = tile_start + r;
        if (gi >= n || r >= TR) continue;
        float ni = norms[gi];
        #pragma unroll
        for (int w = 0; w < 4; ++w) {
            int j = bn + tx * 4 + w;
            if (j >= n) continue;
            sim[(size_t)r * simStride + j] = acc[u][w] / (ni * norms[j]);
        }
    }
}

// per-row exact top-64 (val desc, idx asc) among j>i. One wave per row.
__global__ void __launch_bounds__(64) k_topk(
    const float* __restrict__ sim, int tile_start, int TR, int simStride,
    float* __restrict__ tkV, int* __restrict__ tkI, int* __restrict__ needFix,
    const int* __restrict__ dn)
{
    int n = *dn;
    int r = blockIdx.x;
    int i = tile_start + r;
    if (r >= TR || i >= n) return;
    int lane = threadIdx.x;
    const float* srow = sim + (size_t)r * simStride;

    float v[8]; int id[8];
    #pragma unroll
    for (int u = 0; u < 8; ++u) { v[u] = -INFINITY; id[u] = 0x7fffffff; }
    float ovV = -INFINITY; int ovI = 0x7fffffff;

    for (int j = i + 1 + lane; j < n; j += 64) {
        float x = srow[j];
        if (x > v[7] || (x == v[7] && j < id[7])) {
            if (v[7] > ovV || (v[7] == ovV && id[7] < ovI)) { ovV = v[7]; ovI = id[7]; }
            int p = 7;
            #pragma unroll
            for (int u = 6; u >= 0; --u) {
                bool mv = (x > v[u]) || (x == v[u] && j < id[u]);
                if (mv) { v[u + 1] = v[u]; id[u + 1] = id[u]; p = u; }
            }
            v[p] = x; id[p] = j;
        } else {
            if (x > ovV || (x == ovV && j < ovI)) { ovV = x; ovI = j; }
        }
    }

    int pos = 0;
    float myV = -INFINITY; int myI = 0x7fffffff;
    for (int k = 0; k < TOPK; ++k) {
        float hv = (pos < 8) ? v[pos] : -INFINITY;
        int   hi = (pos < 8) ? id[pos] : 0x7fffffff;
        float bv = hv; int bi = hi;
        #pragma unroll
        for (int o = 1; o < 64; o <<= 1) {
            float xv = __shfl_xor(bv, o, 64);
            int   xi = __shfl_xor(bi, o, 64);
            if (xv > bv || (xv == bv && xi < bi)) { bv = xv; bi = xi; }
        }
        if (pos < 8 && hv == bv && hi == bi) pos++;
        if (k == lane) { myV = bv; myI = bi; }
    }
    tkV[(size_t)i * TOPK + lane] = myV;
    tkI[(size_t)i * TOPK + lane] = myI;

    float v64 = __shfl(myV, 63, 64);
    int   i64 = __shfl(myI, 63, 64);
    float oV = ovV; int oI = ovI;
    #pragma unroll
    for (int o = 1; o < 64; o <<= 1) {
        float xv = __shfl_xor(oV, o, 64);
        int   xi = __shfl_xor(oI, o, 64);
        if (xv > oV || (xv == oV && xi < oI)) { oV = xv; oI = xi; }
    }
    int bad = (oV > v64) || (oV == v64 && oI < i64);
    if (lane == 0) needFix[i] = bad;
}

// rare exact redo: per-lane top-64 lists in LDS (unconditionally exact)
__global__ void __launch_bounds__(64) k_topkfix(
    const float* __restrict__ sim, int tile_start, int TR, int simStride,
    float* __restrict__ tkV, int* __restrict__ tkI, const int* __restrict__ needFix,
    const int* __restrict__ dn)
{
    int n = *dn;
    int r = blockIdx.x;
    int i = tile_start + r;
    if (r >= TR || i >= n) return;
    if (!needFix[i]) return;
    int lane = threadIdx.x;
    __shared__ float lv[64][TOPK];
    __shared__ int   li[64][TOPK];
    for (int u = 0; u < TOPK; ++u) { lv[lane][u] = -INFINITY; li[lane][u] = 0x7fffffff; }
    const float* srow = sim + (size_t)r * simStride;
    for (int j = i + 1 + lane; j < n; j += 64) {
        float x = srow[j];
        float wv = lv[lane][TOPK - 1]; int wi = li[lane][TOPK - 1];
        if (x > wv || (x == wv && j < wi)) {
            int p = TOPK - 1;
            for (int u = TOPK - 2; u >= 0; --u) {
                float uv = lv[lane][u]; int ui = li[lane][u];
                if (x > uv || (x == uv && j < ui)) { lv[lane][u + 1] = uv; li[lane][u + 1] = ui; p = u; }
                else break;
            }
            lv[lane][p] = x; li[lane][p] = j;
        }
    }
    int pos = 0;
    float myV = -INFINITY; int myI = 0x7fffffff;
    for (int k = 0; k < TOPK; ++k) {
        float hv = (pos < TOPK) ? lv[lane][pos] : -INFINITY;
        int   hi = (pos < TOPK) ? li[lane][pos] : 0x7fffffff;
        float bv = hv; int bi = hi;
        #pragma unroll
        for (int o = 1; o < 64; o <<= 1) {
            float xv = __shfl_xor(bv, o, 64);
            int   xi = __shfl_xor(bi, o, 64);
            if (xv > bv || (xv == bv && xi < bi)) { bv = xv; bi = xi; }
        }
        if (pos < TOPK && hv == bv && hi == bi) pos++;
        if (k == lane) { myV = bv; myI = bi; }
    }
    tkV[(size_t)i * TOPK + lane] = myV;
    tkI[(size_t)i * TOPK + lane] = myI;
}

// serial greedy scan, one wave. Register-resident merged bitmask:
// lane owns bits [lane*128, lane*128+128) as two u64. Mask tests are shuffles.
// Only unmerged rows are visited (next-unmerged via ballot+ctz). 6-deep
// register prefetch queue for candidate lists. Hard guard bound makes a
// GPU hang impossible even if the structural termination argument fails.
__global__ void __launch_bounds__(64) k_scan3(
    const float* __restrict__ tkV, const int* __restrict__ tkI,
    const float* __restrict__ E, const float* __restrict__ norms,
    int* __restrict__ partner, int* __restrict__ consumed,
    const int* __restrict__ dn)
{
    const int INF = 0x7fffffff;
    int n = *dn;
    int lane = threadIdx.x;

    // pre-zero consumed; partner is written explicitly for every popped row
    for (int i = lane; i < n; i += 64) consumed[i] = 0;
    __threadfence();   // order pre-zero before later consumed[j]=1 stores

    unsigned long long m0 = 0ull, m1 = 0ull;
    __shared__ unsigned int lm32[NMAX / 32];
    __shared__ int lsCnt;
    __shared__ int lsIdx[2048];

    int tLast = -1;

#define NEXT_UNMERGED(tt, outv) do {                                           \
    int base_ = lane << 7;                                                     \
    unsigned long long u0_ = ~m0, u1_ = ~m1;                                   \
    long long k_ = (long long)(tt) - base_ + 1;                                \
    if (k_ > 0) {                                                              \
        if (k_ >= 128) { u0_ = 0ull; u1_ = 0ull; }                             \
        else if (k_ >= 64) { u0_ = 0ull; if (k_ > 64) u1_ &= (~0ull) << (int)(k_ - 64); } \
        else u0_ &= (~0ull) << (int)k_;                                        \
    }                                                                          \
    int kn_ = n - base_;                                                       \
    if (kn_ <= 0) { u0_ = 0ull; u1_ = 0ull; }                                  \
    else if (kn_ < 64) { u0_ &= (~0ull) >> (64 - kn_); u1_ = 0ull; }           \
    else if (kn_ < 128) { u1_ = (kn_ == 64) ? 0ull : (u1_ & ((~0ull) >> (128 - kn_))); } \
    unsigned long long bal_ = __ballot((u0_ | u1_) != 0ull);                   \
    if (!bal_) { outv = INF; } else {                                          \
        int L_ = __builtin_ctzll(bal_);                                        \
        int cand_;                                                             \
        if (u0_ != 0ull) cand_ = (int)__builtin_ctzll(u0_);                    \
        else if (u1_ != 0ull) cand_ = 64 + (int)__builtin_ctzll(u1_);          \
        else cand_ = 0;                                                        \
        outv = (L_ << 7) + __shfl(cand_, L_, 64);                              \
    }                                                                          \
} while (0)

#define ENQ(qr, qv, qi) do {                                                   \
    int nt_; NEXT_UNMERGED(tLast, nt_);                                        \
    qr = nt_;                                                                  \
    if (nt_ < n) { qv = tkV[(size_t)nt_ * TOPK + lane];                        \
                   qi = tkI[(size_t)nt_ * TOPK + lane]; }                      \
    else { qv = -INFINITY; qi = INF; }                                         \
    tLast = nt_;                                                               \
} while (0)

    int q0r,q1r,q2r,q3r,q4r,q5r;
    float q0v,q1v,q2v,q3v,q4v,q5v;
    int q0i,q1i,q2i,q3i,q4i,q5i;
    ENQ(q0r,q0v,q0i); ENQ(q1r,q1v,q1i); ENQ(q2r,q2v,q2i);
    ENQ(q3r,q3v,q3i); ENQ(q4r,q4v,q4i); ENQ(q5r,q5v,q5i);

    int guard = 2 * NMAX + 64;
    while (q0r != INF && guard-- > 0) {
        int r = q0r;
        // pop-time merged check (r uniform)
        int ro = r >> 7;
        unsigned long long rw0 = __shfl(m0, ro, 64);
        unsigned long long rw1 = __shfl(m1, ro, 64);
        unsigned long long rw = (r & 64) ? rw1 : rw0;
        bool rowMerged = (rw >> (r & 63)) & 1ull;
        if (!rowMerged) {
            int ci = q0i;
            int ow = (ci >> 7) & 63;
            unsigned long long w0 = __shfl(m0, ow, 64);
            unsigned long long w1 = __shfl(m1, ow, 64);
            unsigned long long w = (ci & 64) ? w1 : w0;
            bool valid = (ci < n) && !((w >> (ci & 63)) & 1ull);
            unsigned long long bal = __ballot(valid);
            int j = -1; float bv = -INFINITY;
            if (bal) {
                int L = __builtin_ctzll(bal);   // list sorted desc (val, idx asc)
                j  = __shfl(q0i, L, 64);
                bv = __shfl(q0v, L, 64);
            } else {
                int nx; NEXT_UNMERGED(r, nx);
                if (nx != INF) {
                    // exact fallback over unmerged suffix (rare)
                    ((unsigned long long*)lm32)[2 * lane + 0] = m0;
                    ((unsigned long long*)lm32)[2 * lane + 1] = m1;
                    float ni = norms[r];
                    float4 ei0 = *(const float4*)(E + (size_t)r * D + lane * 8);
                    float4 ei1 = *(const float4*)(E + (size_t)r * D + lane * 8 + 4);
                    float bbv = -INFINITY; int bbj = INF;
                    int w0i = (r + 1) >> 5, wN = (n + 31) >> 5;
                    for (int wb = w0i; wb < wN; wb += 64) {
                        if (lane == 0) lsCnt = 0;
                        int ww = wb + lane;
                        unsigned int um = 0u;
                        if (ww < wN) {
                            um = ~lm32[ww];
                            int jbase = ww << 5;
                            if (jbase <= r) {
                                int k2 = r - jbase + 1;
                                um &= (k2 >= 32) ? 0u : (0xffffffffu << k2);
                            }
                            int over = jbase + 32 - n;
                            if (over > 0) um &= (over >= 32) ? 0u : (0xffffffffu >> over);
                        }
                        while (um) {
                            int b = __builtin_ctz(um);
                            um &= um - 1;
                            lsIdx[atomicAdd(&lsCnt, 1)] = (ww << 5) + b;
                        }
                        int cnt = lsCnt;
                        for (int c = 0; c < cnt; ++c) {
                            int jj = lsIdx[c];
                            float4 a0 = *(const float4*)(E + (size_t)jj * D + lane * 8);
                            float4 a1 = *(const float4*)(E + (size_t)jj * D + lane * 8 + 4);
                            float s = ei0.x * a0.x + ei0.y * a0.y + ei0.z * a0.z + ei0.w * a0.w
                                    + ei1.x * a1.x + ei1.y * a1.y + ei1.z * a1.z + ei1.w * a1.w;
                            #pragma unroll
                            for (int o = 1; o < 64; o <<= 1) s += __shfl_xor(s, o, 64);
                            float sv = s / (ni * norms[jj]);
                            if (sv > bbv || (sv == bbv && jj < bbj)) { bbv = sv; bbj = jj; }
                        }
                    }
                    if (bbj != INF) { bv = bbv; j = bbj; }
                }
            }
            bool ok = (j >= 0) && (bv >= THRESH);
            if (ok) {
                if (lane == (r >> 7)) { if (r & 64) m1 |= 1ull << (r & 63); else m0 |= 1ull << (r & 63); }
                if (lane == (j >> 7)) { if (j & 64) m1 |= 1ull << (j & 63); else m0 |= 1ull << (j & 63); }
                if (lane == 0) { partner[r] = j; consumed[j] = 1; }
            } else {
                if (lane == 0) partner[r] = -1;
            }
        }
        // rotate queue, refill tail
        q0r=q1r; q0v=q1v; q0i=q1i;
        q1r=q2r; q1v=q2v; q1i=q2i;
        q2r=q3r; q2v=q3v; q2i=q3i;
        q3r=q4r; q3v=q4v; q3i=q4i;
        q4r=q5r; q4v=q5v; q4i=q5i;
        ENQ(q5r,q5v,q5i);
    }
#undef ENQ
#undef NEXT_UNMERGED
}

// survivor compaction plan: srcIdx[k] = i for each surviving row, dn <- newN
__global__ void __launch_bounds__(1024)
k_compact_plan(const int* __restrict__ consumed, int* __restrict__ srcIdx,
               int* __restrict__ dn) {
    int n = *dn;
    int t = threadIdx.x;
    __shared__ int lds[1024];
    __shared__ int base;
    if (t == 0) base = 0;
    __syncthreads();
    for (int c0 = 0; c0 < n; c0 += 1024) {
        int i = c0 + t;
        int f = (i < n) ? (consumed[i] ? 0 : 1) : 0;
        lds[t] = f;
        __syncthreads();
        for (int o = 1; o < 1024; o <<= 1) {
            int v = (t >= o) ? lds[t - o] : 0;
            __syncthreads();
            lds[t] += v;
            __syncthreads();
        }
        if (f) srcIdx[base + lds[t] - 1] = i;
        __syncthreads();
        if (t == 0) base += lds[1023];
        __syncthreads();
    }
    if (t == 0) *dn = base;
}

// fused[i] = partner>=0 ? min(e_i + e_p, 1) : e_i ; compact into nxt
__global__ void k_fuse(const float* __restrict__ cur, float* __restrict__ nxt,
                       const int* __restrict__ srcIdx, const int* __restrict__ partner,
                       const int* __restrict__ dn) {
    int nn = *dn;            // new count (already updated)
    int k = blockIdx.x;
    if (k >= nn) return;
    int t = threadIdx.x;     // 0..127
    int i = srcIdx[k];
    int p = partner[i];
    float4 v = ((const float4*)(cur + (size_t)i * D))[t];
    if (p >= 0) {
        float4 w = ((const float4*)(cur + (size_t)p * D))[t];
        v.x = fminf(v.x + w.x, 1.0f);
        v.y = fminf(v.y + w.y, 1.0f);
        v.z = fminf(v.z + w.z, 1.0f);
        v.w = fminf(v.w + w.w, 1.0f);
    }
    ((float4*)(nxt + (size_t)k * D))[t] = v;
}

__global__ void k_copyout(const float* __restrict__ src, float* __restrict__ dst, int nelem) {
    int i = blockIdx.x * 256 + threadIdx.x;
    if (i < nelem) dst[i] = src[i];
}

extern "C" void kernel_launch(void* const* d_in, const int* in_sizes, int n_in,
                              void* d_out, int out_size, void* d_ws, size_t ws_size,
                              hipStream_t stream) {
    const float* input = (const float*)d_in[0];
    const int N0 = in_sizes[0] / D;   // 8192
    char* ws = (char*)d_ws;

    // round 0 reads d_in directly; bufA holds <=N0/2 rows, bufB <=N0/4 rows
    const size_t embA = (size_t)(N0 / 2) * D * sizeof(float);   // 8 MB
    const size_t embB = (size_t)(N0 / 4) * D * sizeof(float);   // 4 MB
    float* bufA = (float*)ws;
    float* bufB = (float*)(ws + embA);
    char*  aux  = ws + embA + embB;
    float* norms        = (float*)(aux);
    int*   partner      = (int*)(aux + 32 * 1024);
    int*   consumed     = (int*)(aux + 64 * 1024);
    int*   srcIdx       = (int*)(aux + 96 * 1024);
    int*   dn           = (int*)(aux + 128 * 1024);
    int*   needFix      = (int*)(aux + 160 * 1024);
    float* tkV          = (float*)(aux + 256 * 1024);
    int*   tkI          = (int*)(aux + 256 * 1024 + (size_t)NMAX * TOPK * 4);
    float* simTile      = (float*)(aux + 256 * 1024 + 2 * (size_t)NMAX * TOPK * 4);
    const size_t fixedBytes = embA + embB + 256 * 1024 + 2 * (size_t)NMAX * TOPK * 4;

    int TR = NMAX;
    while (TR > 64 && fixedBytes + (size_t)TR * N0 * sizeof(float) > ws_size) TR >>= 1;

    const int ROUNDS = 16;
    k_init<<<1, 1, 0, stream>>>(dn, N0);
    for (int r = 0; r < ROUNDS; ++r) {
        const float* cur = (r == 0) ? input : ((r & 1) ? bufA : bufB);
        float* nxt = (r & 1) ? bufB : bufA;
        k_norms<<<N0, 128, 0, stream>>>(cur, norms, dn);
        int NT = N0 / TR;
        for (int t = 0; t < NT; ++t) {
            dim3 g(N0 / BN, TR / BM);
            k_simtile<<<g, dim3(16, 16), 0, stream>>>(cur, norms, simTile, t * TR, TR, N0, dn);
            k_topk<<<TR, 64, 0, stream>>>(simTile, t * TR, TR, N0, tkV, tkI, needFix, dn);
            k_topkfix<<<TR, 64, 0, stream>>>(simTile, t * TR, TR, N0, tkV, tkI, needFix, dn);
        }
        k_scan3<<<1, 64, 0, stream>>>(tkV, tkI, cur, norms, partner, consumed, dn);
        k_compact_plan<<<1, 1024, 0, stream>>>(consumed, srcIdx, dn);
        k_fuse<<<N0, 128, 0, stream>>>(cur, nxt, srcIdx, partner, dn);
    }
    float* fin = bufB;   // ROUNDS-1 = 15 is odd -> last write went to bufB
    k_copyout<<<(out_size + 255) / 256, 256, 0, stream>>>(fin, (float*)d_out, out_size);
}

// Round 5
// 15591.173 us; speedup vs baseline: 3.4133x; 1.4386x over previous
//
#include <hip/hip_runtime.h>
#include <math.h>

#define D 512
#define THRESH 0.5f
#define NMAX 8192
#define TOPK 64

typedef short bhalf8 __attribute__((ext_vector_type(8)));
typedef float f32x4 __attribute__((ext_vector_type(4)));

__global__ void k_init(int* dn, int n) { *dn = n; }

// one block (128 threads) per row: norm = max(||row||, 1e-8)
__global__ void k_norms(const float* __restrict__ embs, float* __restrict__ norms,
                        const int* __restrict__ dn) {
    int n = *dn;
    int row = blockIdx.x;
    if (row >= n) return;
    int t = threadIdx.x; // 0..127
    float4 v = ((const float4*)(embs + (size_t)row * D))[t];
    float s = v.x * v.x + v.y * v.y + v.z * v.z + v.w * v.w;
    #pragma unroll
    for (int o = 32; o > 0; o >>= 1) s += __shfl_down(s, o, 64);
    __shared__ float ls[2];
    if ((t & 63) == 0) ls[t >> 6] = s;
    __syncthreads();
    if (t == 0) norms[row] = fmaxf(sqrtf(ls[0] + ls[1]), 1e-8f);
}

// fp32 -> bf16 (RNE) conversion of current embeddings, 8 per thread
__global__ void k_tobf16(const float* __restrict__ in, unsigned short* __restrict__ out,
                         const int* __restrict__ dn) {
    int n = *dn;
    size_t total = (size_t)n * D;
    size_t idx = ((size_t)blockIdx.x * 256 + threadIdx.x) * 8;
    if (idx >= total) return;
    float4 f0 = *(const float4*)(in + idx);
    float4 f1 = *(const float4*)(in + idx + 4);
    unsigned short r[8];
    float f[8] = {f0.x, f0.y, f0.z, f0.w, f1.x, f1.y, f1.z, f1.w};
    #pragma unroll
    for (int u = 0; u < 8; ++u) {
        unsigned int b = __float_as_uint(f[u]);
        r[u] = (unsigned short)((b + 0x7FFFu + ((b >> 16) & 1u)) >> 16);
    }
    uint4 packed;
    packed.x = (unsigned)r[0] | ((unsigned)r[1] << 16);
    packed.y = (unsigned)r[2] | ((unsigned)r[3] << 16);
    packed.z = (unsigned)r[4] | ((unsigned)r[5] << 16);
    packed.w = (unsigned)r[6] | ((unsigned)r[7] << 16);
    *(uint4*)(out + idx) = packed;
}

// sim tile via bf16 MFMA: 128x128 block tile, 4 waves (2x2), BK=64, K=512.
// sim[r][j] = dot(E[i],E[j]) / (norms[i]*norms[j]) for tile rows.
#define LDSTRIDE 72   // shorts per LDS row (128B data + 16B pad -> ~2-way banks)
__global__ void __launch_bounds__(256) k_mfma_sim(
    const unsigned short* __restrict__ H, const float* __restrict__ norms,
    float* __restrict__ sim, int tile_start, int TR, int simStride,
    const int* __restrict__ dn)
{
    int n = *dn;
    if (tile_start >= n) return;
    int row0 = tile_start + blockIdx.y * 128;   // i panel (global)
    int col0 = blockIdx.x * 128;                // j panel (global)
    if (row0 >= n || col0 >= n) return;
    if (col0 + 128 <= row0 + 1) return;         // triangle skip (need j > i)

    __shared__ unsigned short As[128 * LDSTRIDE];
    __shared__ unsigned short Bs[128 * LDSTRIDE];
    int tid = threadIdx.x;
    int lane = tid & 63;
    int wave = tid >> 6;          // 0..3
    int wr = wave >> 1;           // 0..1
    int wc = wave & 1;            // 0..1
    int krow = lane & 15;
    int kgrp = (lane >> 4) * 8;

    f32x4 acc[4][4];
    #pragma unroll
    for (int m = 0; m < 4; ++m)
        #pragma unroll
        for (int t = 0; t < 4; ++t)
            acc[m][t] = (f32x4){0.f, 0.f, 0.f, 0.f};

    for (int k0 = 0; k0 < D; k0 += 64) {
        // stage A and B tiles: 128 rows x 64 cols bf16 each
        #pragma unroll
        for (int it = 0; it < 4; ++it) {
            int c  = tid + it * 256;      // 0..1023 (16B chunks)
            int rr = c >> 3;              // row 0..127
            int cc = c & 7;               // 16B chunk in row
            uint4 va = make_uint4(0, 0, 0, 0);
            int gra = row0 + rr;
            if (gra < n) va = *(const uint4*)(H + (size_t)gra * D + k0 + cc * 8);
            *(uint4*)&As[rr * LDSTRIDE + cc * 8] = va;
            uint4 vb = make_uint4(0, 0, 0, 0);
            int grb = col0 + rr;
            if (grb < n) vb = *(const uint4*)(H + (size_t)grb * D + k0 + cc * 8);
            *(uint4*)&Bs[rr * LDSTRIDE + cc * 8] = vb;
        }
        __syncthreads();
        #pragma unroll
        for (int kk = 0; kk < 64; kk += 32) {
            bhalf8 a[4], b[4];
            #pragma unroll
            for (int m = 0; m < 4; ++m)
                a[m] = *(const bhalf8*)&As[(wr * 64 + m * 16 + krow) * LDSTRIDE + kk + kgrp];
            #pragma unroll
            for (int t = 0; t < 4; ++t)
                b[t] = *(const bhalf8*)&Bs[(wc * 64 + t * 16 + krow) * LDSTRIDE + kk + kgrp];
            #pragma unroll
            for (int m = 0; m < 4; ++m)
                #pragma unroll
                for (int t = 0; t < 4; ++t)
                    acc[m][t] = __builtin_amdgcn_mfma_f32_16x16x32_bf16(a[m], b[t], acc[m][t], 0, 0, 0);
        }
        __syncthreads();
    }

    // epilogue: D frag mapping col=lane&15, row=(lane>>4)*4+v
    int fcol = lane & 15;
    int frow = (lane >> 4) * 4;
    #pragma unroll
    for (int m = 0; m < 4; ++m) {
        #pragma unroll
        for (int t = 0; t < 4; ++t) {
            #pragma unroll
            for (int v = 0; v < 4; ++v) {
                int gr = row0 + wr * 64 + m * 16 + frow + v;
                int gc = col0 + wc * 64 + t * 16 + fcol;
                if (gr < n && gc < n)
                    sim[(size_t)(gr - tile_start) * simStride + gc] =
                        acc[m][t][v] / (norms[gr] * norms[gc]);
            }
        }
    }
}

// per-row exact top-64 (val desc, idx asc) among j>i. One wave per row.
// Writes packed {valbits, idx} pairs. Overflow watermark flags rare redo.
__global__ void __launch_bounds__(64) k_topk(
    const float* __restrict__ sim, int tile_start, int TR, int simStride,
    uint2* __restrict__ tkP, int* __restrict__ needFix,
    const int* __restrict__ dn)
{
    int n = *dn;
    int r = blockIdx.x;
    int i = tile_start + r;
    if (r >= TR || i >= n) return;
    int lane = threadIdx.x;
    const float* srow = sim + (size_t)r * simStride;

    float v[8]; int id[8];
    #pragma unroll
    for (int u = 0; u < 8; ++u) { v[u] = -INFINITY; id[u] = 0x7fffffff; }
    float ovV = -INFINITY; int ovI = 0x7fffffff;

    for (int j = i + 1 + lane; j < n; j += 64) {
        float x = srow[j];
        if (x > v[7] || (x == v[7] && j < id[7])) {
            if (v[7] > ovV || (v[7] == ovV && id[7] < ovI)) { ovV = v[7]; ovI = id[7]; }
            int p = 7;
            #pragma unroll
            for (int u = 6; u >= 0; --u) {
                bool mv = (x > v[u]) || (x == v[u] && j < id[u]);
                if (mv) { v[u + 1] = v[u]; id[u + 1] = id[u]; p = u; }
            }
            v[p] = x; id[p] = j;
        } else {
            if (x > ovV || (x == ovV && j < ovI)) { ovV = x; ovI = j; }
        }
    }

    int pos = 0;
    float myV = -INFINITY; int myI = 0x7fffffff;
    for (int k = 0; k < TOPK; ++k) {
        float hv = (pos < 8) ? v[pos] : -INFINITY;
        int   hi = (pos < 8) ? id[pos] : 0x7fffffff;
        float bv = hv; int bi = hi;
        #pragma unroll
        for (int o = 1; o < 64; o <<= 1) {
            float xv = __shfl_xor(bv, o, 64);
            int   xi = __shfl_xor(bi, o, 64);
            if (xv > bv || (xv == bv && xi < bi)) { bv = xv; bi = xi; }
        }
        if (pos < 8 && hv == bv && hi == bi) pos++;
        if (k == lane) { myV = bv; myI = bi; }
    }
    tkP[(size_t)i * TOPK + lane] = make_uint2(__float_as_uint(myV), (unsigned)myI);

    float v64 = __shfl(myV, 63, 64);
    int   i64 = __shfl(myI, 63, 64);
    float oV = ovV; int oI = ovI;
    #pragma unroll
    for (int o = 1; o < 64; o <<= 1) {
        float xv = __shfl_xor(oV, o, 64);
        int   xi = __shfl_xor(oI, o, 64);
        if (xv > oV || (xv == oV && xi < oI)) { oV = xv; oI = xi; }
    }
    int bad = (oV > v64) || (oV == v64 && oI < i64);
    if (lane == 0) needFix[i] = bad;
}

// rare exact redo: per-lane top-64 lists in LDS (unconditionally exact)
__global__ void __launch_bounds__(64) k_topkfix(
    const float* __restrict__ sim, int tile_start, int TR, int simStride,
    uint2* __restrict__ tkP, const int* __restrict__ needFix,
    const int* __restrict__ dn)
{
    int n = *dn;
    int r = blockIdx.x;
    int i = tile_start + r;
    if (r >= TR || i >= n) return;
    if (!needFix[i]) return;
    int lane = threadIdx.x;
    __shared__ float lv[64][TOPK];
    __shared__ int   li[64][TOPK];
    for (int u = 0; u < TOPK; ++u) { lv[lane][u] = -INFINITY; li[lane][u] = 0x7fffffff; }
    const float* srow = sim + (size_t)r * simStride;
    for (int j = i + 1 + lane; j < n; j += 64) {
        float x = srow[j];
        float wv = lv[lane][TOPK - 1]; int wi = li[lane][TOPK - 1];
        if (x > wv || (x == wv && j < wi)) {
            int p = TOPK - 1;
            for (int u = TOPK - 2; u >= 0; --u) {
                float uv = lv[lane][u]; int ui = li[lane][u];
                if (x > uv || (x == uv && j < ui)) { lv[lane][u + 1] = uv; li[lane][u + 1] = ui; p = u; }
                else break;
            }
            lv[lane][p] = x; li[lane][p] = j;
        }
    }
    int pos = 0;
    float myV = -INFINITY; int myI = 0x7fffffff;
    for (int k = 0; k < TOPK; ++k) {
        float hv = (pos < TOPK) ? lv[lane][pos] : -INFINITY;
        int   hi = (pos < TOPK) ? li[lane][pos] : 0x7fffffff;
        float bv = hv; int bi = hi;
        #pragma unroll
        for (int o = 1; o < 64; o <<= 1) {
            float xv = __shfl_xor(bv, o, 64);
            int   xi = __shfl_xor(bi, o, 64);
            if (xv > bv || (xv == bv && xi < bi)) { bv = xv; bi = xi; }
        }
        if (pos < TOPK && hv == bv && hi == bi) pos++;
        if (k == lane) { myV = bv; myI = bi; }
    }
    tkP[(size_t)i * TOPK + lane] = make_uint2(__float_as_uint(myV), (unsigned)myI);
}

// serial greedy scan, one wave. Register merged-bitmask (128 bits/lane).
// Double-buffered batches of 8 rows: build+load next batch BEFORE popping
// current, so the 8 independent candidate-list loads complete under the
// ~8 pops of shuffle/ballot work. Pop-time re-check keeps semantics exact.
__global__ void __launch_bounds__(64) k_scan4(
    const uint2* __restrict__ tkP,
    const float* __restrict__ E, const float* __restrict__ norms,
    int* __restrict__ partner, int* __restrict__ consumed,
    const int* __restrict__ dn)
{
    const int INF = 0x7fffffff;
    int n = *dn;
    int lane = threadIdx.x;

    for (int i = lane; i < n; i += 64) consumed[i] = 0;
    __threadfence();

    unsigned long long m0 = 0ull, m1 = 0ull;
    __shared__ unsigned int lm32[NMAX / 32];
    __shared__ int lsCnt;
    __shared__ int lsIdx[2048];

    int tLast = -1;

#define NEXT_UNMERGED(tt, outv) do {                                           \
    int base_ = lane << 7;                                                     \
    unsigned long long u0_ = ~m0, u1_ = ~m1;                                   \
    long long k_ = (long long)(tt) - base_ + 1;                                \
    if (k_ > 0) {                                                              \
        if (k_ >= 128) { u0_ = 0ull; u1_ = 0ull; }                             \
        else if (k_ >= 64) { u0_ = 0ull; if (k_ > 64) u1_ &= (~0ull) << (int)(k_ - 64); } \
        else u0_ &= (~0ull) << (int)k_;                                        \
    }                                                                          \
    int kn_ = n - base_;                                                       \
    if (kn_ <= 0) { u0_ = 0ull; u1_ = 0ull; }                                  \
    else if (kn_ < 64) { u0_ &= (~0ull) >> (64 - kn_); u1_ = 0ull; }           \
    else if (kn_ < 128) { u1_ = (kn_ == 64) ? 0ull : (u1_ & ((~0ull) >> (128 - kn_))); } \
    unsigned long long bal_ = __ballot((u0_ | u1_) != 0ull);                   \
    if (!bal_) { outv = INF; } else {                                          \
        int L_ = __builtin_ctzll(bal_);                                        \
        int cand_;                                                             \
        if (u0_ != 0ull) cand_ = (int)__builtin_ctzll(u0_);                    \
        else if (u1_ != 0ull) cand_ = 64 + (int)__builtin_ctzll(u1_);          \
        else cand_ = 0;                                                        \
        outv = (L_ << 7) + __shfl(cand_, L_, 64);                              \
    }                                                                          \
} while (0)

    int  selA[8]; uint2 cA[8];
    int  selB[8]; uint2 cB[8];

    #pragma unroll
    for (int k = 0; k < 8; ++k) {
        int nt; NEXT_UNMERGED(tLast, nt);
        selA[k] = nt;
        cA[k] = (nt < n) ? tkP[(size_t)nt * TOPK + lane]
                         : make_uint2(0xFF800000u, (unsigned)INF);
        tLast = nt;
    }

    int guard = NMAX + 64;
    while (selA[0] != INF && guard-- > 0) {
        // build + load next batch (stale mask OK; pop-time re-check below)
        #pragma unroll
        for (int k = 0; k < 8; ++k) {
            int nt; NEXT_UNMERGED(tLast, nt);
            selB[k] = nt;
            cB[k] = (nt < n) ? tkP[(size_t)nt * TOPK + lane]
                             : make_uint2(0xFF800000u, (unsigned)INF);
            tLast = nt;
        }
        // pop current batch
        #pragma unroll
        for (int k = 0; k < 8; ++k) {
            int r = selA[k];
            if (r == INF) continue;
            int ro = r >> 7;
            unsigned long long rw0 = __shfl(m0, ro, 64);
            unsigned long long rw1 = __shfl(m1, ro, 64);
            unsigned long long rw = (r & 64) ? rw1 : rw0;
            if ((rw >> (r & 63)) & 1ull) continue;      // merged since enqueue

            int   ci = (int)cA[k].y;
            float cv = __uint_as_float(cA[k].x);
            int ow = (ci >> 7) & 63;
            unsigned long long w0 = __shfl(m0, ow, 64);
            unsigned long long w1 = __shfl(m1, ow, 64);
            unsigned long long w = (ci & 64) ? w1 : w0;
            bool valid = (ci < n) && !((w >> (ci & 63)) & 1ull);
            unsigned long long bal = __ballot(valid);
            int j = -1; float bv = -INFINITY;
            if (bal) {
                int L = __builtin_ctzll(bal);   // sorted: lowest lane = lex-max
                j  = (int)__shfl(ci, L, 64);
                bv = __shfl(cv, L, 64);
            } else {
                int nx; NEXT_UNMERGED(r, nx);
                if (nx != INF) {
                    // exact fallback over unmerged suffix (rare)
                    ((unsigned long long*)lm32)[2 * lane + 0] = m0;
                    ((unsigned long long*)lm32)[2 * lane + 1] = m1;
                    float ni = norms[r];
                    float4 ei0 = *(const float4*)(E + (size_t)r * D + lane * 8);
                    float4 ei1 = *(const float4*)(E + (size_t)r * D + lane * 8 + 4);
                    float bbv = -INFINITY; int bbj = INF;
                    int w0i = (r + 1) >> 5, wN = (n + 31) >> 5;
                    for (int wb = w0i; wb < wN; wb += 64) {
                        if (lane == 0) lsCnt = 0;
                        int ww = wb + lane;
                        unsigned int um = 0u;
                        if (ww < wN) {
                            um = ~lm32[ww];
                            int jbase = ww << 5;
                            if (jbase <= r) {
                                int k2 = r - jbase + 1;
                                um &= (k2 >= 32) ? 0u : (0xffffffffu << k2);
                            }
                            int over = jbase + 32 - n;
                            if (over > 0) um &= (over >= 32) ? 0u : (0xffffffffu >> over);
                        }
                        while (um) {
                            int b = __builtin_ctz(um);
                            um &= um - 1;
                            lsIdx[atomicAdd(&lsCnt, 1)] = (ww << 5) + b;
                        }
                        int cnt = lsCnt;
                        for (int c = 0; c < cnt; ++c) {
                            int jj = lsIdx[c];
                            float4 a0 = *(const float4*)(E + (size_t)jj * D + lane * 8);
                            float4 a1 = *(const float4*)(E + (size_t)jj * D + lane * 8 + 4);
                            float s = ei0.x * a0.x + ei0.y * a0.y + ei0.z * a0.z + ei0.w * a0.w
                                    + ei1.x * a1.x + ei1.y * a1.y + ei1.z * a1.z + ei1.w * a1.w;
                            #pragma unroll
                            for (int o = 1; o < 64; o <<= 1) s += __shfl_xor(s, o, 64);
                            float sv = s / (ni * norms[jj]);
                            if (sv > bbv || (sv == bbv && jj < bbj)) { bbv = sv; bbj = jj; }
                        }
                    }
                    if (bbj != INF) { bv = bbv; j = bbj; }
                }
            }
            bool ok = (j >= 0) && (bv >= THRESH);
            if (ok) {
                if (lane == (r >> 7)) { if (r & 64) m1 |= 1ull << (r & 63); else m0 |= 1ull << (r & 63); }
                if (lane == (j >> 7)) { if (j & 64) m1 |= 1ull << (j & 63); else m0 |= 1ull << (j & 63); }
                if (lane == 0) { partner[r] = j; consumed[j] = 1; }
            } else {
                if (lane == 0) partner[r] = -1;
            }
        }
        // rotate batches
        #pragma unroll
        for (int k = 0; k < 8; ++k) { selA[k] = selB[k]; cA[k] = cB[k]; }
    }
#undef NEXT_UNMERGED
}

// survivor compaction plan: srcIdx[k] = i for each surviving row, dn <- newN
__global__ void __launch_bounds__(1024)
k_compact_plan(const int* __restrict__ consumed, int* __restrict__ srcIdx,
               int* __restrict__ dn) {
    int n = *dn;
    int t = threadIdx.x;
    __shared__ int lds[1024];
    __shared__ int base;
    if (t == 0) base = 0;
    __syncthreads();
    for (int c0 = 0; c0 < n; c0 += 1024) {
        int i = c0 + t;
        int f = (i < n) ? (consumed[i] ? 0 : 1) : 0;
        lds[t] = f;
        __syncthreads();
        for (int o = 1; o < 1024; o <<= 1) {
            int v = (t >= o) ? lds[t - o] : 0;
            __syncthreads();
            lds[t] += v;
            __syncthreads();
        }
        if (f) srcIdx[base + lds[t] - 1] = i;
        __syncthreads();
        if (t == 0) base += lds[1023];
        __syncthreads();
    }
    if (t == 0) *dn = base;
}

// fused[i] = partner>=0 ? min(e_i + e_p, 1) : e_i ; compact into nxt
__global__ void k_fuse(const float* __restrict__ cur, float* __restrict__ nxt,
                       const int* __restrict__ srcIdx, const int* __restrict__ partner,
                       const int* __restrict__ dn) {
    int nn = *dn;            // new count (already updated)
    int k = blockIdx.x;
    if (k >= nn) return;
    int t = threadIdx.x;     // 0..127
    int i = srcIdx[k];
    int p = partner[i];
    float4 v = ((const float4*)(cur + (size_t)i * D))[t];
    if (p >= 0) {
        float4 w = ((const float4*)(cur + (size_t)p * D))[t];
        v.x = fminf(v.x + w.x, 1.0f);
        v.y = fminf(v.y + w.y, 1.0f);
        v.z = fminf(v.z + w.z, 1.0f);
        v.w = fminf(v.w + w.w, 1.0f);
    }
    ((float4*)(nxt + (size_t)k * D))[t] = v;
}

__global__ void k_copyout(const float* __restrict__ src, float* __restrict__ dst, int nelem) {
    int i = blockIdx.x * 256 + threadIdx.x;
    if (i < nelem) dst[i] = src[i];
}

extern "C" void kernel_launch(void* const* d_in, const int* in_sizes, int n_in,
                              void* d_out, int out_size, void* d_ws, size_t ws_size,
                              hipStream_t stream) {
    const float* input = (const float*)d_in[0];
    const int N0 = in_sizes[0] / D;   // 8192
    char* ws = (char*)d_ws;

    const size_t embA = (size_t)(N0 / 2) * D * sizeof(float);   // 8 MB
    const size_t embB = (size_t)(N0 / 4) * D * sizeof(float);   // 4 MB
    const size_t embH = (size_t)N0 * D * sizeof(unsigned short); // 8 MB
    float* bufA = (float*)ws;
    float* bufB = (float*)(ws + embA);
    unsigned short* curh = (unsigned short*)(ws + embA + embB);
    char* aux = ws + embA + embB + embH;
    float* norms   = (float*)(aux);
    int*   partner = (int*)(aux + 32 * 1024);
    int*   consumed= (int*)(aux + 64 * 1024);
    int*   srcIdx  = (int*)(aux + 96 * 1024);
    int*   dn      = (int*)(aux + 128 * 1024);
    int*   needFix = (int*)(aux + 160 * 1024);
    uint2* tkP     = (uint2*)(aux + 256 * 1024);
    float* simTile = (float*)(aux + 256 * 1024 + (size_t)NMAX * TOPK * 8);
    const size_t fixedBytes = embA + embB + embH + 256 * 1024 + (size_t)NMAX * TOPK * 8;

    int TR = NMAX;
    while (TR > 128 && fixedBytes + (size_t)TR * N0 * sizeof(float) > ws_size) TR >>= 1;

    const int ROUNDS = 16;
    k_init<<<1, 1, 0, stream>>>(dn, N0);
    for (int r = 0; r < ROUNDS; ++r) {
        const float* cur = (r == 0) ? input : ((r & 1) ? bufA : bufB);
        float* nxt = (r & 1) ? bufB : bufA;
        k_norms<<<N0, 128, 0, stream>>>(cur, norms, dn);
        k_tobf16<<<(N0 * D / 8 + 255) / 256, 256, 0, stream>>>(cur, curh, dn);
        int NT = N0 / TR;
        for (int t = 0; t < NT; ++t) {
            dim3 g(N0 / 128, TR / 128);
            k_mfma_sim<<<g, 256, 0, stream>>>(curh, norms, simTile, t * TR, TR, N0, dn);
            k_topk<<<TR, 64, 0, stream>>>(simTile, t * TR, TR, N0, tkP, needFix, dn);
            k_topkfix<<<TR, 64, 0, stream>>>(simTile, t * TR, TR, N0, tkP, needFix, dn);
        }
        k_scan4<<<1, 64, 0, stream>>>(tkP, cur, norms, partner, consumed, dn);
        k_compact_plan<<<1, 1024, 0, stream>>>(consumed, srcIdx, dn);
        k_fuse<<<N0, 128, 0, stream>>>(cur, nxt, srcIdx, partner, dn);
    }
    float* fin = bufB;   // ROUNDS-1 = 15 is odd -> last write went to bufB
    k_copyout<<<(out_size + 255) / 256, 256, 0, stream>>>(fin, (float*)d_out, out_size);
}